// Round 10
// baseline (257.254 us; speedup 1.0000x reference)
//
#include <hip/hip_runtime.h>
#include <hip/hip_bf16.h>

// LSTM B=8192,T=512,I=3,H=25 + linear[H->1], bf16 MFMA 16x16x32.
// R22 = R19 + CU-TICKET ANTI-PHASE. R21's blockIdx-parity stagger was a
// null because it GUESSED the co-residency pairing; if the dispatcher fills
// depth-first within an XCD (pairs (i,i+8)), both blocks of a pair got the
// same parity. Fix: wave 0 of each block reads its physical CU identity
// (HW_ID bits[15:8] + XCC_ID) and takes an atomic ticket from a per-CU
// workspace slot; ARRIVAL ORDER determines phase. Second arrival sleeps
// ~448cy (half of the measured 914cy step period) so its issue-dense
// window covers the partner's read->MFMA->acts chain window forever after
// (identical periods -> offset conserved; contention slows both equally).
// Parity is self-maintaining across launches (each launch adds exactly 2
// tickets/CU -> consecutive tickets split odd/even), so no ws init needed.
// Everything else identical to R19 (195us measured): 4-wave blocks, 1 chain
// per block, per-wave 2 MFMA row-blocks, frag-linear LDS, merged-denominator
// c-update, v2f pk glue, lgkmcnt-only barrier, register x ping-pong.

#define TSTEPS 512
#define ISZ 3
#define HSZ 25

typedef __attribute__((ext_vector_type(8))) short bf16x8;
typedef __attribute__((ext_vector_type(4))) float f32x4;
typedef __attribute__((ext_vector_type(4))) int i32x4;
typedef __attribute__((ext_vector_type(2))) float v2f;

__device__ __forceinline__ unsigned short bf16_bits(float v) {
    return __builtin_bit_cast(unsigned short, __float2bfloat16(v));
}
__device__ __forceinline__ unsigned int pack_bf16(float lo, float hi) {
    return ((unsigned int)bf16_bits(hi) << 16) | (unsigned int)bf16_bits(lo);
}
__device__ __forceinline__ v2f rcp2(v2f v) {
    return (v2f){__builtin_amdgcn_rcpf(v.x), __builtin_amdgcn_rcpf(v.y)};
}

__global__ __launch_bounds__(256, 2) void lstm_mfma(
    const float* __restrict__ x,      // [B, T, I]
    const float* __restrict__ w_ih,   // [4H, I]
    const float* __restrict__ w_hh,   // [4H, H]
    const float* __restrict__ b_ih,   // [4H]
    const float* __restrict__ b_hh,   // [4H]
    const float* __restrict__ w_lin,  // [1, H]
    const float* __restrict__ b_lin,  // [1]
    float* __restrict__ out,          // [B, 1]
    unsigned* __restrict__ ws,        // >=8KB: per-CU ticket slots
    int has_ws)
{
    // frag-linear: short idx (k,n) = (k>>3)*128 + n*8 + (k&7); real frag is
    // idx 0..511 (k<32); 512..767 is scrap for the jb=7 block's writes.
    __shared__ short hb[2][768];
    __shared__ float outred[4][16];
    __shared__ int phase_sh;

    const int tid  = threadIdx.x;
    const int w    = tid >> 6;        // wave 0..3
    const int lane = tid & 63;
    const int n    = lane & 15;       // batch col
    const int q    = lane >> 4;       // quad -> k-slots 8q..8q+7
    const int b0   = blockIdx.x * 16;

    const float K1 = 1.442695040888963f;   // log2 e
    const float K2 = 2.885390081777927f;   // 2 log2 e

    for (int i = tid; i < 2 * 768; i += 256) ((short*)hb)[i] = 0;

    // ---- CU-arrival ticket: physical CU key -> atomic ticket -> phase ----
    if (tid == 0) {
        int ph = 0;
        if (has_ws) {
            unsigned hwid, xcc;
            asm volatile("s_getreg_b32 %0, hwreg(HW_REG_HW_ID)" : "=s"(hwid));
            asm volatile("s_getreg_b32 %0, hwreg(HW_REG_XCC_ID)" : "=s"(xcc));
            const unsigned key = ((xcc & 7u) << 8) | ((hwid >> 8) & 0xFFu);
            ph = (int)(atomicAdd(&ws[key], 1u) & 1u);
        }
        phase_sh = ph;
    }

    // ---- A fragments for row-blocks jbA=w, jbB=w+4 (jb=7 all-zero) ----
    // Within a block: MFMA row rr=n -> unit 4*jb + (n>>2), gate n&3.
    // k map: 0..2 w_ih, 3 bias, 4..28 w_hh col k-4, 29..31 pad.
    bf16x8 afA, afB;
    {
        const int g = n & 3, us = n >> 2;
        const int uA = 4 * w + us;            // <= 15, always valid
        const int uB = 4 * (w + 4) + us;      // 16..31, guard < 25
        #pragma unroll
        for (int j = 0; j < 8; ++j) {
            const int k = q * 8 + j;
            float vA = 0.f, vB = 0.f;
            {
                const int orow = g * HSZ + uA;
                if (k < ISZ)            vA = w_ih[orow * ISZ + k];
                else if (k == ISZ)      vA = b_ih[orow] + b_hh[orow];
                else if (k < 4 + HSZ)   vA = w_hh[orow * HSZ + (k - 4)];
                vA *= (g == 2) ? -K2 : -K1;
            }
            if (uB < HSZ) {
                const int orow = g * HSZ + uB;
                if (k < ISZ)            vB = w_ih[orow * ISZ + k];
                else if (k == ISZ)      vB = b_ih[orow] + b_hh[orow];
                else if (k < 4 + HSZ)   vB = w_hh[orow * HSZ + (k - 4)];
                vB *= (g == 2) ? -K2 : -K1;
            }
            afA[j] = (short)bf16_bits(vA);
            afB[j] = (short)bf16_bits(vB);
        }
    }

    // ---- write slots: unit u=4jb+q -> k=u+4 (pads/scrap land harmlessly) --
    const int uwA = 4 * w + q;                 // <= 15
    const int uwB = 4 * (w + 4) + q;           // 16..31 (>=25 -> pad/scrap)
    const int kwA = uwA + 4, kwB = uwB + 4;    // kwB <= 35 -> scrap region
    const int woffA = (kwA >> 3) * 128 + n * 8 + (kwA & 7);
    const int woffB = (kwB >> 3) * 128 + n * 8 + (kwB & 7);
    const int rdoff = lane * 8;

    v2f c = {0.f, 0.f}, h = {0.f, 0.f};

    // ---- x prefetch: 3 x float4 per 4-step group, reg ping-pong ----
    const float* __restrict__ xg = x + (size_t)(b0 + n) * (TSTEPS * ISZ);
    float4 a0 = ((const float4*)xg)[0];
    float4 a1 = ((const float4*)xg)[1];
    float4 a2 = ((const float4*)xg)[2];

    __syncthreads();   // zeros + phase_sh visible

    // ---- anti-phase: second arrival on this CU delays ~448cy (half of the
    // measured 914cy step period); offset conserved thereafter.
    if (phase_sh) {
        asm volatile("s_sleep 7" ::: "memory");
    }

    auto step = [&](int rp, float x0, float x1, float x2) {
        // linear ds_read_b128; q0 lanes insert x/bias from registers
        bf16x8 frag = *(const bf16x8*)&hb[rp][rdoff];
        i32x4 fi = __builtin_bit_cast(i32x4, frag);
        const int px0 = (int)pack_bf16(x0, x1);
        const int px1 = (int)pack_bf16(x2, 1.0f);
        fi[0] = (q == 0) ? px0 : fi[0];
        fi[1] = (q == 0) ? px1 : fi[1];
        frag = __builtin_bit_cast(bf16x8, fi);

        const f32x4 zc = {0.f, 0.f, 0.f, 0.f};
        const f32x4 aA = __builtin_amdgcn_mfma_f32_16x16x32_bf16(afA, frag, zc, 0, 0, 0);
        const f32x4 aB = __builtin_amdgcn_mfma_f32_16x16x32_bf16(afB, frag, zc, 0, 0, 0);

        // acts (prescaled): 14 trans; glue packed v2f across (A,B) blocks
        const v2f e0 = {__builtin_amdgcn_exp2f(aA[0]), __builtin_amdgcn_exp2f(aB[0])};
        const v2f e1 = {__builtin_amdgcn_exp2f(aA[1]), __builtin_amdgcn_exp2f(aB[1])};
        const v2f e2 = {__builtin_amdgcn_exp2f(fminf(aA[2], 126.f)),
                        __builtin_amdgcn_exp2f(fminf(aB[2], 126.f))};
        const v2f e3 = {__builtin_amdgcn_exp2f(aA[3]), __builtin_amdgcn_exp2f(aB[3])};
        const v2f one = {1.f, 1.f};
        const v2f s0 = e0 + one, s1 = e1 + one, s2 = e2 + one, m2 = one - e2;
        const v2f p02 = s0 * s2;
        const v2f num = c * p02 + m2 * s1;     // merged-denominator c-update
        const v2f den = p02 * s1;
        c = num * rcp2(den);
        const v2f ec = {__builtin_amdgcn_exp2f(fminf(-K2 * c.x, 126.f)),
                        __builtin_amdgcn_exp2f(fminf(-K2 * c.y, 126.f))};
        const v2f hden = (e3 + one) * (ec + one);
        h = (one - ec) * rcp2(hden);

        const int wp = rp ^ 1;
        hb[wp][woffA] = (short)bf16_bits(h.x);
        hb[wp][woffB] = (short)bf16_bits(h.y);   // pad/scrap-slot trick
        // retire DS writes, then barrier; vmcnt (x prefetch) stays in flight
        asm volatile("s_waitcnt lgkmcnt(0)" ::: "memory");
        __builtin_amdgcn_s_barrier();
    };

    #pragma unroll 1
    for (int g = 0; g < 128; g += 2) {
        const float4* __restrict__ p1 =
            (const float4*)(xg + (size_t)((g + 1 < 128 ? g + 1 : 127) * 12));
        const float4 n0 = p1[0], n1 = p1[1], n2 = p1[2];
        step(0, a0.x, a0.y, a0.z);
        step(1, a0.w, a1.x, a1.y);
        step(0, a1.z, a1.w, a2.x);
        step(1, a2.y, a2.z, a2.w);
        const float4* __restrict__ p2 =
            (const float4*)(xg + (size_t)((g + 2 < 128 ? g + 2 : 127) * 12));
        a0 = p2[0]; a1 = p2[1]; a2 = p2[2];
        step(0, n0.x, n0.y, n0.z);
        step(1, n0.w, n1.x, n1.y);
        step(0, n1.z, n1.w, n2.x);
        step(1, n2.y, n2.z, n2.w);
    }

    // ---- final linear: out[b] = sum_u w_lin[u]*h[u] + b_lin ----
    const float wlA = (uwA < HSZ) ? w_lin[uwA] : 0.f;
    const float wlB = (uwB < HSZ) ? w_lin[uwB] : 0.f;
    float v = wlA * h.x + wlB * h.y;
    v += __shfl_xor(v, 16);
    v += __shfl_xor(v, 32);
    if (lane < 16) outred[w][lane] = v;
    __syncthreads();
    if (tid < 16) {
        float s = b_lin[0];
        #pragma unroll
        for (int k2 = 0; k2 < 4; ++k2) s += outred[k2][tid];
        out[b0 + tid] = s;
    }
}

extern "C" void kernel_launch(void* const* d_in, const int* in_sizes, int n_in,
                              void* d_out, int out_size, void* d_ws, size_t ws_size,
                              hipStream_t stream) {
    const float* x     = (const float*)d_in[0];
    const float* w_ih  = (const float*)d_in[1];
    const float* w_hh  = (const float*)d_in[2];
    const float* b_ih  = (const float*)d_in[3];
    const float* b_hh  = (const float*)d_in[4];
    const float* w_lin = (const float*)d_in[5];
    const float* b_lin = (const float*)d_in[6];
    float* out = (float*)d_out;
    unsigned* ws = (unsigned*)d_ws;
    const int has_ws = (ws != nullptr && ws_size >= 8192) ? 1 : 0;

    lstm_mfma<<<8192 / 16, 256, 0, stream>>>(x, w_ih, w_hh, b_ih, b_hh,
                                             w_lin, b_lin, out, ws, has_ws);
}